// Round 1
// baseline (1128.131 us; speedup 1.0000x reference)
//
#include <hip/hip_runtime.h>
#include <math.h>

#define B_ 4
#define N_ 500
#define K_ 50
#define D_ 2048
#define IMG_ 224

// ---------------- distance matrix: dist[b][n] = ||q_b - bank_n|| ----------------
__global__ void dist_kernel(const float* __restrict__ x2, const float* __restrict__ f2,
                            float* __restrict__ dist) {
  const int n = blockIdx.x, b = blockIdx.y;
  const float* q = x2 + (size_t)b * D_;
  const float* r = f2 + (size_t)n * D_;
  float s = 0.f;
  for (int c = threadIdx.x; c < D_; c += 256) {
    float d = q[c] - r[c];
    s += d * d;
  }
  for (int o = 32; o; o >>= 1) s += __shfl_down(s, o);
  __shared__ float part[4];
  const int lane = threadIdx.x & 63, wv = threadIdx.x >> 6;
  if (lane == 0) part[wv] = s;
  __syncthreads();
  if (threadIdx.x == 0)
    dist[b * N_ + n] = sqrtf(part[0] + part[1] + part[2] + part[3]);
}

// ---------------- top-K smallest (one wave per batch) ----------------
__global__ void topk_kernel(const float* __restrict__ dist, int* __restrict__ idx,
                            float* __restrict__ score) {
  const int b = blockIdx.x;
  const int lane = threadIdx.x;  // 64 threads = 1 wave
  float v[8];
  int id[8];
  int cnt = 0;
  for (int n = lane; n < N_; n += 64) { v[cnt] = dist[b * N_ + n]; id[cnt] = n; cnt++; }
  for (int c = cnt; c < 8; c++) { v[c] = INFINITY; id[c] = -1; }
  float ssum = 0.f;
  for (int k = 0; k < K_; k++) {
    float bestv = v[0];
    int besti = 0;
#pragma unroll
    for (int c = 1; c < 8; c++)
      if (v[c] < bestv) { bestv = v[c]; besti = c; }
    // distances are >= 0 so float bits order as uint; low bits = lane (unique -> no ties)
    unsigned long long key =
        ((unsigned long long)__float_as_uint(bestv) << 32) | (unsigned)lane;
    for (int o = 32; o; o >>= 1) {
      unsigned long long other = __shfl_xor(key, o);
      if (other < key) key = other;
    }
    const int wl = (int)(key & 63u);
    const float wvmin = __uint_as_float((unsigned)(key >> 32));
    if (lane == wl) {
      idx[b * K_ + k] = id[besti];
      v[besti] = INFINITY;
    }
    ssum += wvmin;
  }
  if (lane == 0) score[b] = ssum / (float)K_;
}

// ---------------- per-position min over K gathered rows ----------------
// one block of 4 waves per (b,h,w); wave wv handles k = wv, wv+4, ...
template <int C, int H>
__global__ __launch_bounds__(256) void mindist_kernel(
    const float* __restrict__ f, const float* __restrict__ x,
    const int* __restrict__ idx, float* __restrict__ m) {
  const int p = blockIdx.x;  // b*H*H + hw
  const int b = p / (H * H);
  const int hw = p % (H * H);
  const int lane = threadIdx.x & 63;
  const int wv = threadIdx.x >> 6;
  constexpr int V = C / 256;  // float4 loads per lane
  const float4* xrow = (const float4*)(x + ((size_t)b * H * H + hw) * C);
  float4 xv[V];
#pragma unroll
  for (int i = 0; i < V; i++) xv[i] = xrow[lane + i * 64];
  float best = INFINITY;
  for (int k = wv; k < K_; k += 4) {
    const int n = idx[b * K_ + k];
    const float4* frow = (const float4*)(f + ((size_t)n * H * H + hw) * C);
    float s = 0.f;
#pragma unroll
    for (int i = 0; i < V; i++) {
      float4 fv = frow[lane + i * 64];
      float d0 = fv.x - xv[i].x, d1 = fv.y - xv[i].y;
      float d2 = fv.z - xv[i].z, d3 = fv.w - xv[i].w;
      s += d0 * d0 + d1 * d1 + d2 * d2 + d3 * d3;
    }
    for (int o = 32; o; o >>= 1) s += __shfl_down(s, o);
    if (lane == 0) best = fminf(best, s);
  }
  __shared__ float red[4];
  if (lane == 0) red[wv] = best;
  __syncthreads();
  if (threadIdx.x == 0)
    m[p] = sqrtf(fminf(fminf(red[0], red[1]), fminf(red[2], red[3])));
}

// ---------------- gaussian kernel weights (33 taps, sigma=4) ----------------
__global__ void gk_kernel(float* __restrict__ gk) {
  __shared__ float w[33];
  const int t = threadIdx.x;
  if (t < 33) {
    float xx = (float)t - 16.f;
    w[t] = expf(-(xx * xx) / 32.f);  // 2*sigma^2 = 32
  }
  __syncthreads();
  if (t == 0) {
    float s = 0.f;
    for (int i = 0; i < 33; i++) s += w[i];
    for (int i = 0; i < 33; i++) gk[i] = w[i] / s;
  }
}

// ---------------- bilinear upsample (JAX half-pixel, clamped) + average ----------------
__device__ inline float bilerp(const float* __restrict__ m, int H, int i, int j) {
  const float scale = (float)H / (float)IMG_;
  float ty = fminf(fmaxf(((float)i + 0.5f) * scale - 0.5f, 0.f), (float)(H - 1));
  float tx = fminf(fmaxf(((float)j + 0.5f) * scale - 0.5f, 0.f), (float)(H - 1));
  const int y0 = (int)ty, x0 = (int)tx;
  const int y1 = y0 + 1 < H ? y0 + 1 : H - 1;
  const int x1 = x0 + 1 < H ? x0 + 1 : H - 1;
  const float wy = ty - (float)y0, wx = tx - (float)x0;
  const float a = m[y0 * H + x0] * (1.f - wx) + m[y0 * H + x1] * wx;
  const float c = m[y1 * H + x0] * (1.f - wx) + m[y1 * H + x1] * wx;
  return a * (1.f - wy) + c * wy;
}

__global__ void upsample_kernel(const float* __restrict__ m0, const float* __restrict__ m1,
                                float* __restrict__ up) {
  const int t = blockIdx.x * 256 + threadIdx.x;
  if (t >= B_ * IMG_ * IMG_) return;
  const int b = t / (IMG_ * IMG_);
  const int r = t % (IMG_ * IMG_);
  const int i = r / IMG_, j = r % IMG_;
  const float a0 = bilerp(m0 + b * 28 * 28, 28, i, j);
  const float a1 = bilerp(m1 + b * 14 * 14, 14, i, j);
  up[t] = 0.5f * (a0 + a1);
}

__device__ inline int reflect101(int t) {
  t = t < 0 ? -t : t;
  t = t > IMG_ - 1 ? 2 * (IMG_ - 1) - t : t;
  return t;
}

__global__ void blurH_kernel(const float* __restrict__ up, float* __restrict__ tmp,
                             const float* __restrict__ gk) {
  const int t = blockIdx.x * 256 + threadIdx.x;
  if (t >= B_ * IMG_ * IMG_) return;
  const int b = t / (IMG_ * IMG_);
  const int r = t % (IMG_ * IMG_);
  const int i = r / IMG_, j = r % IMG_;
  float s = 0.f;
#pragma unroll
  for (int o = 0; o < 33; o++) {
    const int y = reflect101(i - 16 + o);
    s += gk[o] * up[(b * IMG_ + y) * IMG_ + j];
  }
  tmp[t] = s;
}

__global__ void blurW_kernel(const float* __restrict__ tmp, float* __restrict__ outm,
                             const float* __restrict__ gk) {
  const int t = blockIdx.x * 256 + threadIdx.x;
  if (t >= B_ * IMG_ * IMG_) return;
  const int b = t / (IMG_ * IMG_);
  const int r = t % (IMG_ * IMG_);
  const int i = r / IMG_, j = r % IMG_;
  float s = 0.f;
#pragma unroll
  for (int o = 0; o < 33; o++) {
    const int xx = reflect101(j - 16 + o);
    s += gk[o] * tmp[(b * IMG_ + i) * IMG_ + xx];
  }
  outm[t] = s;
}

extern "C" void kernel_launch(void* const* d_in, const int* in_sizes, int n_in,
                              void* d_out, int out_size, void* d_ws, size_t ws_size,
                              hipStream_t stream) {
  const float* x0 = (const float*)d_in[0];  // [4,28,28,512]
  const float* x1 = (const float*)d_in[1];  // [4,14,14,1024]
  const float* x2 = (const float*)d_in[2];  // [4,1,1,2048]
  const float* f0 = (const float*)d_in[3];  // [500,28,28,512]
  const float* f1 = (const float*)d_in[4];  // [500,14,14,1024]
  const float* f2 = (const float*)d_in[5];  // [500,1,1,2048]
  float* out = (float*)d_out;               // [4] score + [4*224*224] mask

  float* ws = (float*)d_ws;
  float* dist = ws;                  // 2000
  int* idxb = (int*)(ws + 2000);     // 200
  float* m0 = ws + 2200;             // 3136
  float* m1 = ws + 5336;             // 784
  float* gk = ws + 6120;             // 33 (pad to 40)
  float* up = ws + 6160;             // 200704
  float* tmp = ws + 206864;          // 200704

  dist_kernel<<<dim3(N_, B_), 256, 0, stream>>>(x2, f2, dist);
  topk_kernel<<<B_, 64, 0, stream>>>(dist, idxb, out);  // writes score -> out[0..3]
  gk_kernel<<<1, 64, 0, stream>>>(gk);
  mindist_kernel<512, 28><<<B_ * 28 * 28, 256, 0, stream>>>(f0, x0, idxb, m0);
  mindist_kernel<1024, 14><<<B_ * 14 * 14, 256, 0, stream>>>(f1, x1, idxb, m1);
  const int npix = B_ * IMG_ * IMG_;  // 200704
  upsample_kernel<<<npix / 256, 256, 0, stream>>>(m0, m1, up);
  blurH_kernel<<<npix / 256, 256, 0, stream>>>(up, tmp, gk);
  blurW_kernel<<<npix / 256, 256, 0, stream>>>(tmp, out + B_, gk);
}